// Round 1
// baseline (1300.531 us; speedup 1.0000x reference)
//
#include <hip/hip_runtime.h>
#include <math.h>

typedef __bf16 bf16x8 __attribute__((ext_vector_type(8)));
typedef float f32x4 __attribute__((ext_vector_type(4)));

#define MTOT 32768   // B*N
#define DD   1024
#define NSEQ 4096
#define BB   8

__device__ __forceinline__ void async16(const void* gp, void* lp) {
  __builtin_amdgcn_global_load_lds(
      (__attribute__((address_space(1))) void*)(const_cast<void*>(gp)),
      (__attribute__((address_space(3))) void*)(lp), 16, 0, 0);
}

__device__ __forceinline__ unsigned short f2bf(float f) {
  union { float f; unsigned int u; } v; v.f = f;
  unsigned int r = v.u + 0x7fffu + ((v.u >> 16) & 1u);
  return (unsigned short)(r >> 16);
}
__device__ __forceinline__ float bf2f(unsigned short u) {
  union { unsigned int u; float f; } v; v.u = ((unsigned int)u) << 16; return v.f;
}

// ---------------- fp32 -> bf16 convert ----------------
__global__ void cvt_bf16(const float* __restrict__ in, unsigned short* __restrict__ out, int n) {
  int i = (blockIdx.x * blockDim.x + threadIdx.x) * 8;
  if (i >= n) return;
  float4 a = *(const float4*)(in + i);
  float4 b = *(const float4*)(in + i + 4);
  ushort4 o0, o1;
  o0.x = f2bf(a.x); o0.y = f2bf(a.y); o0.z = f2bf(a.z); o0.w = f2bf(a.w);
  o1.x = f2bf(b.x); o1.y = f2bf(b.y); o1.z = f2bf(b.z); o1.w = f2bf(b.w);
  *(ushort4*)(out + i) = o0;
  *(ushort4*)(out + i + 4) = o1;
}

// ---------------- K/Q projection GEMM: C = X @ W^T + b, bf16 out ----------------
__global__ __launch_bounds__(256) void proj_kq(
    const unsigned short* __restrict__ xb,
    const unsigned short* __restrict__ Wk, const unsigned short* __restrict__ Wq,
    const float* __restrict__ bk, const float* __restrict__ bq,
    unsigned short* __restrict__ Kbuf, unsigned short* __restrict__ Qbuf) {
  const int m0 = blockIdx.x * 128;
  const int n0 = blockIdx.y * 128;
  const unsigned short* W = blockIdx.z ? Wq : Wk;
  const float* bias = blockIdx.z ? bq : bk;
  unsigned short* out = blockIdx.z ? Qbuf : Kbuf;

  __shared__ __align__(16) unsigned short As[128 * 32];
  __shared__ __align__(16) unsigned short Bs[128 * 32];

  const int tid = threadIdx.x;
  const int w = tid >> 6, lane = tid & 63;
  const int wm = w >> 1, wn = w & 1;
  const int lq = lane >> 4, lr = lane & 15;
  const int srow = lane >> 2, scol = (lane & 3) * 8;

  f32x4 acc[4][4];
#pragma unroll
  for (int i = 0; i < 4; i++)
#pragma unroll
    for (int j = 0; j < 4; j++) acc[i][j] = (f32x4)(0.f);

  for (int k0 = 0; k0 < 1024; k0 += 32) {
#pragma unroll
    for (int s = 0; s < 2; s++) {
      int c = w * 2 + s;
      int row = c * 16 + srow;
      async16(xb + (size_t)(m0 + row) * 1024 + k0 + scol, (char*)As + c * 1024 + lane * 16);
      async16(W  + (size_t)(n0 + row) * 1024 + k0 + scol, (char*)Bs + c * 1024 + lane * 16);
    }
    __syncthreads();
    bf16x8 af[4], bfr[4];
#pragma unroll
    for (int i = 0; i < 4; i++) af[i]  = *(const bf16x8*)(As + (wm * 64 + i * 16 + lr) * 32 + lq * 8);
#pragma unroll
    for (int j = 0; j < 4; j++) bfr[j] = *(const bf16x8*)(Bs + (wn * 64 + j * 16 + lr) * 32 + lq * 8);
#pragma unroll
    for (int i = 0; i < 4; i++)
#pragma unroll
      for (int j = 0; j < 4; j++)
        acc[i][j] = __builtin_amdgcn_mfma_f32_16x16x32_bf16(af[i], bfr[j], acc[i][j], 0, 0, 0);
    __syncthreads();
  }
#pragma unroll
  for (int j = 0; j < 4; j++) {
    int col = n0 + wn * 64 + j * 16 + lr;
    float bv = bias[col];
#pragma unroll
    for (int i = 0; i < 4; i++) {
      int rowb = m0 + wm * 64 + i * 16 + lq * 4;
#pragma unroll
      for (int r = 0; r < 4; r++)
        out[(size_t)(rowb + r) * 1024 + col] = f2bf(acc[i][j][r] + bv);
    }
  }
}

// ---------------- value projection: dual GEMM + GLU ----------------
__global__ __launch_bounds__(256) void proj_v(
    const unsigned short* __restrict__ xb,
    const unsigned short* __restrict__ Wvr, const unsigned short* __restrict__ Wvi,
    const float* __restrict__ bvr, const float* __restrict__ bvi,
    unsigned short* __restrict__ Vbuf) {
  const int m0 = blockIdx.x * 128;
  const int n0 = blockIdx.y * 128;

  __shared__ __align__(16) unsigned short As[128 * 32];
  __shared__ __align__(16) unsigned short Bs[128 * 32];
  __shared__ __align__(16) unsigned short Bs2[128 * 32];

  const int tid = threadIdx.x;
  const int w = tid >> 6, lane = tid & 63;
  const int wm = w >> 1, wn = w & 1;
  const int lq = lane >> 4, lr = lane & 15;
  const int srow = lane >> 2, scol = (lane & 3) * 8;

  f32x4 accR[4][4], accI[4][4];
#pragma unroll
  for (int i = 0; i < 4; i++)
#pragma unroll
    for (int j = 0; j < 4; j++) { accR[i][j] = (f32x4)(0.f); accI[i][j] = (f32x4)(0.f); }

  for (int k0 = 0; k0 < 1024; k0 += 32) {
#pragma unroll
    for (int s = 0; s < 2; s++) {
      int c = w * 2 + s;
      int row = c * 16 + srow;
      async16(xb  + (size_t)(m0 + row) * 1024 + k0 + scol, (char*)As  + c * 1024 + lane * 16);
      async16(Wvr + (size_t)(n0 + row) * 1024 + k0 + scol, (char*)Bs  + c * 1024 + lane * 16);
      async16(Wvi + (size_t)(n0 + row) * 1024 + k0 + scol, (char*)Bs2 + c * 1024 + lane * 16);
    }
    __syncthreads();
    bf16x8 af[4], br[4], bi[4];
#pragma unroll
    for (int i = 0; i < 4; i++) af[i] = *(const bf16x8*)(As  + (wm * 64 + i * 16 + lr) * 32 + lq * 8);
#pragma unroll
    for (int j = 0; j < 4; j++) br[j] = *(const bf16x8*)(Bs  + (wn * 64 + j * 16 + lr) * 32 + lq * 8);
#pragma unroll
    for (int j = 0; j < 4; j++) bi[j] = *(const bf16x8*)(Bs2 + (wn * 64 + j * 16 + lr) * 32 + lq * 8);
#pragma unroll
    for (int i = 0; i < 4; i++)
#pragma unroll
      for (int j = 0; j < 4; j++) {
        accR[i][j] = __builtin_amdgcn_mfma_f32_16x16x32_bf16(af[i], br[j], accR[i][j], 0, 0, 0);
        accI[i][j] = __builtin_amdgcn_mfma_f32_16x16x32_bf16(af[i], bi[j], accI[i][j], 0, 0, 0);
      }
    __syncthreads();
  }
#pragma unroll
  for (int j = 0; j < 4; j++) {
    int col = n0 + wn * 64 + j * 16 + lr;
    float br_ = bvr[col], bi_ = bvi[col];
#pragma unroll
    for (int i = 0; i < 4; i++) {
      int rowb = m0 + wm * 64 + i * 16 + lq * 4;
#pragma unroll
      for (int r = 0; r < 4; r++) {
        float vr = accR[i][j][r] + br_;
        float vi = accI[i][j][r] + bi_;
        float sp = (vi > 15.f) ? vi : log1pf(expf(vi));
        Vbuf[(size_t)(rowb + r) * 1024 + col] = f2bf(vr * tanhf(sp));
      }
    }
  }
}

// ---------------- tiled transpose [b][n][d] -> [b][d][n] ----------------
__global__ void transpose_kq(const unsigned short* __restrict__ Kbuf,
                             const unsigned short* __restrict__ Qbuf,
                             unsigned short* __restrict__ Kt,
                             unsigned short* __restrict__ Qt) {
  __shared__ unsigned short tile[64][65];
  int n0 = blockIdx.x * 64, d0 = blockIdx.y * 64;
  int b = blockIdx.z & 7, which = blockIdx.z >> 3;
  const unsigned short* src = (which ? Qbuf : Kbuf) + (size_t)b * NSEQ * DD;
  unsigned short* dst = (which ? Qt : Kt) + (size_t)b * DD * NSEQ;
  int tx = threadIdx.x, ty = threadIdx.y;
#pragma unroll
  for (int i = 0; i < 64; i += 4)
    tile[ty + i][tx] = src[(size_t)(n0 + ty + i) * DD + d0 + tx];
  __syncthreads();
#pragma unroll
  for (int i = 0; i < 64; i += 4)
    dst[(size_t)(d0 + ty + i) * NSEQ + n0 + tx] = tile[tx][ty + i];
}

// ---------------- per-channel reciprocal norms ----------------
__global__ __launch_bounds__(256) void colnorm(const unsigned short* __restrict__ Kt,
                                               const unsigned short* __restrict__ Qt,
                                               float* __restrict__ rn) {
  int row = blockIdx.x;          // b*1024 + chan
  int which = blockIdx.y;        // 0 = K, 1 = Q
  const unsigned short* src = (which ? Qt : Kt) + (size_t)row * NSEQ;
  float s = 0.f;
  for (int i = threadIdx.x; i < NSEQ; i += 256) { float v = bf2f(src[i]); s += v * v; }
  for (int off = 32; off; off >>= 1) s += __shfl_down(s, off, 64);
  __shared__ float wsum[4];
  int w = threadIdx.x >> 6, lane = threadIdx.x & 63;
  if (lane == 0) wsum[w] = s;
  __syncthreads();
  if (threadIdx.x == 0) {
    float t = wsum[0] + wsum[1] + wsum[2] + wsum[3];
    rn[which * (BB * DD) + row] = 1.f / (sqrtf(t) + 1e-5f);
  }
}

// ---------------- feature attention: fat[b][e][d] = smu(scale * q_e . k_d) ----------------
__global__ __launch_bounds__(256) void attn_gemm(
    const unsigned short* __restrict__ Qt, const unsigned short* __restrict__ Kt,
    const float* __restrict__ rn, unsigned short* __restrict__ fat) {
  const int b = blockIdx.z;
  const int e0 = blockIdx.y * 128;  // rows (query chan)
  const int d0 = blockIdx.x * 128;  // cols (key chan)
  const unsigned short* A  = Qt + (size_t)b * DD * NSEQ;
  const unsigned short* Bm = Kt + (size_t)b * DD * NSEQ;
  unsigned short* out = fat + (size_t)b * DD * DD;

  __shared__ __align__(16) unsigned short As[128 * 32];
  __shared__ __align__(16) unsigned short Bs[128 * 32];

  const int tid = threadIdx.x;
  const int w = tid >> 6, lane = tid & 63;
  const int wm = w >> 1, wn = w & 1;
  const int lq = lane >> 4, lr = lane & 15;
  const int srow = lane >> 2, scol = (lane & 3) * 8;

  f32x4 acc[4][4];
#pragma unroll
  for (int i = 0; i < 4; i++)
#pragma unroll
    for (int j = 0; j < 4; j++) acc[i][j] = (f32x4)(0.f);

  for (int k0 = 0; k0 < NSEQ; k0 += 32) {
#pragma unroll
    for (int s = 0; s < 2; s++) {
      int c = w * 2 + s;
      int row = c * 16 + srow;
      async16(A  + (size_t)(e0 + row) * NSEQ + k0 + scol, (char*)As + c * 1024 + lane * 16);
      async16(Bm + (size_t)(d0 + row) * NSEQ + k0 + scol, (char*)Bs + c * 1024 + lane * 16);
    }
    __syncthreads();
    bf16x8 af[4], bfr[4];
#pragma unroll
    for (int i = 0; i < 4; i++) af[i]  = *(const bf16x8*)(As + (wm * 64 + i * 16 + lr) * 32 + lq * 8);
#pragma unroll
    for (int j = 0; j < 4; j++) bfr[j] = *(const bf16x8*)(Bs + (wn * 64 + j * 16 + lr) * 32 + lq * 8);
#pragma unroll
    for (int i = 0; i < 4; i++)
#pragma unroll
      for (int j = 0; j < 4; j++)
        acc[i][j] = __builtin_amdgcn_mfma_f32_16x16x32_bf16(af[i], bfr[j], acc[i][j], 0, 0, 0);
    __syncthreads();
  }
#pragma unroll
  for (int j = 0; j < 4; j++) {
    int col = d0 + wn * 64 + j * 16 + lr;
    float rk = rn[b * DD + col];
#pragma unroll
    for (int i = 0; i < 4; i++) {
      int rowb = e0 + wm * 64 + i * 16 + lq * 4;
#pragma unroll
      for (int r = 0; r < 4; r++) {
        float rq = rn[BB * DD + b * DD + rowb + r];
        float c = acc[i][j][r] * rq * rk;
        c = (c > 0.f) ? c : 0.25f * c;   // smu with mu=1e6 == leaky relu (erf saturated)
        out[(size_t)(rowb + r) * DD + col] = f2bf(c);
      }
    }
  }
}

// ---------------- output GEMM: out[m][e] = sum_d V[m][d] * fa[d][e] (fat holds fa^T) ----------------
__global__ __launch_bounds__(256) void out_gemm(
    const unsigned short* __restrict__ V, const unsigned short* __restrict__ fat,
    float* __restrict__ out) {
  const int m0 = blockIdx.x * 128;
  const int e0 = blockIdx.y * 128;
  const int b = m0 >> 12;  // /4096
  const unsigned short* Bm = fat + (size_t)b * DD * DD;

  __shared__ __align__(16) unsigned short As[128 * 32];
  __shared__ __align__(16) unsigned short Bs[128 * 32];

  const int tid = threadIdx.x;
  const int w = tid >> 6, lane = tid & 63;
  const int wm = w >> 1, wn = w & 1;
  const int lq = lane >> 4, lr = lane & 15;
  const int srow = lane >> 2, scol = (lane & 3) * 8;

  f32x4 acc[4][4];
#pragma unroll
  for (int i = 0; i < 4; i++)
#pragma unroll
    for (int j = 0; j < 4; j++) acc[i][j] = (f32x4)(0.f);

  for (int k0 = 0; k0 < DD; k0 += 32) {
#pragma unroll
    for (int s = 0; s < 2; s++) {
      int c = w * 2 + s;
      int row = c * 16 + srow;
      async16(V  + (size_t)(m0 + row) * DD + k0 + scol, (char*)As + c * 1024 + lane * 16);
      async16(Bm + (size_t)(e0 + row) * DD + k0 + scol, (char*)Bs + c * 1024 + lane * 16);
    }
    __syncthreads();
    bf16x8 af[4], bfr[4];
#pragma unroll
    for (int i = 0; i < 4; i++) af[i]  = *(const bf16x8*)(As + (wm * 64 + i * 16 + lr) * 32 + lq * 8);
#pragma unroll
    for (int j = 0; j < 4; j++) bfr[j] = *(const bf16x8*)(Bs + (wn * 64 + j * 16 + lr) * 32 + lq * 8);
#pragma unroll
    for (int i = 0; i < 4; i++)
#pragma unroll
      for (int j = 0; j < 4; j++)
        acc[i][j] = __builtin_amdgcn_mfma_f32_16x16x32_bf16(af[i], bfr[j], acc[i][j], 0, 0, 0);
    __syncthreads();
  }
#pragma unroll
  for (int j = 0; j < 4; j++) {
    int col = e0 + wn * 64 + j * 16 + lr;
#pragma unroll
    for (int i = 0; i < 4; i++) {
      int rowb = m0 + wm * 64 + i * 16 + lq * 4;
#pragma unroll
      for (int r = 0; r < 4; r++)
        out[(size_t)(rowb + r) * DD + col] = acc[i][j][r];
    }
  }
}

extern "C" void kernel_launch(void* const* d_in, const int* in_sizes, int n_in,
                              void* d_out, int out_size, void* d_ws, size_t ws_size,
                              hipStream_t stream) {
  const float* x   = (const float*)d_in[0];
  const float* Wvr = (const float*)d_in[1];
  const float* bvr = (const float*)d_in[2];
  const float* Wvi = (const float*)d_in[3];
  const float* bvi = (const float*)d_in[4];
  const float* Wk  = (const float*)d_in[5];
  const float* bk  = (const float*)d_in[6];
  const float* Wq  = (const float*)d_in[7];
  const float* bq  = (const float*)d_in[8];
  float* out = (float*)d_out;

  char* p = (char*)d_ws;
  unsigned short* xb = (unsigned short*)p; p += (size_t)MTOT * DD * 2;     // 64 MiB
  unsigned short* Wb = (unsigned short*)p; p += 4ull * DD * DD * 2;        // 8 MiB
  unsigned short* Kt = (unsigned short*)p; p += (size_t)BB * DD * NSEQ * 2; // 64 MiB
  unsigned short* Qt = (unsigned short*)p; p += (size_t)BB * DD * NSEQ * 2; // 64 MiB
  unsigned short* Vb = (unsigned short*)p; p += (size_t)MTOT * DD * 2;     // 64 MiB
  unsigned short* fat = (unsigned short*)p; p += (size_t)BB * DD * DD * 2; // 16 MiB
  float* rn = (float*)p; p += 2ull * BB * DD * sizeof(float);              // 64 KiB

  // K,Q (natural layout, bf16) staged inside d_out scratch: 2 * 64 MiB == out buffer
  unsigned short* Kbuf = (unsigned short*)d_out;
  unsigned short* Qbuf = Kbuf + (size_t)MTOT * DD;

  int nx = MTOT * DD;        // 33,554,432
  int nw = DD * DD;          // 1,048,576
  cvt_bf16<<<nx / 8 / 256, 256, 0, stream>>>(x, xb, nx);
  cvt_bf16<<<nw / 8 / 256, 256, 0, stream>>>(Wvr, Wb + 0ull * nw, nw);
  cvt_bf16<<<nw / 8 / 256, 256, 0, stream>>>(Wvi, Wb + 1ull * nw, nw);
  cvt_bf16<<<nw / 8 / 256, 256, 0, stream>>>(Wk,  Wb + 2ull * nw, nw);
  cvt_bf16<<<nw / 8 / 256, 256, 0, stream>>>(Wq,  Wb + 3ull * nw, nw);

  proj_kq<<<dim3(MTOT / 128, DD / 128, 2), 256, 0, stream>>>(
      xb, Wb + 2ull * nw, Wb + 3ull * nw, bk, bq, Kbuf, Qbuf);
  proj_v<<<dim3(MTOT / 128, DD / 128), 256, 0, stream>>>(
      xb, Wb + 0ull * nw, Wb + 1ull * nw, bvr, bvi, Vb);

  transpose_kq<<<dim3(NSEQ / 64, DD / 64, 16), dim3(64, 4), 0, stream>>>(Kbuf, Qbuf, Kt, Qt);
  colnorm<<<dim3(BB * DD, 2), 256, 0, stream>>>(Kt, Qt, rn);

  attn_gemm<<<dim3(DD / 128, DD / 128, BB), 256, 0, stream>>>(Qt, Kt, rn, fat);
  out_gemm<<<dim3(MTOT / 128, DD / 128), 256, 0, stream>>>(Vb, fat, out);
}

// Round 2
// 979.304 us; speedup vs baseline: 1.3280x; 1.3280x over previous
//
#include <hip/hip_runtime.h>
#include <math.h>

typedef __bf16 bf16x8 __attribute__((ext_vector_type(8)));
typedef float f32x4 __attribute__((ext_vector_type(4)));

#define MTOT 32768   // B*N
#define DD   1024
#define NSEQ 4096
#define BB   8

__device__ __forceinline__ void async16(const void* gp, void* lp) {
  __builtin_amdgcn_global_load_lds(
      (__attribute__((address_space(1))) void*)(const_cast<void*>(gp)),
      (__attribute__((address_space(3))) void*)(lp), 16, 0, 0);
}

__device__ __forceinline__ unsigned short f2bf(float f) {
  union { float f; unsigned int u; } v; v.f = f;
  unsigned int r = v.u + 0x7fffu + ((v.u >> 16) & 1u);
  return (unsigned short)(r >> 16);
}
__device__ __forceinline__ float bf2f(unsigned short u) {
  union { unsigned int u; float f; } v; v.u = ((unsigned int)u) << 16; return v.f;
}

// ---------------- fp32 -> bf16 convert ----------------
__global__ void cvt_bf16(const float* __restrict__ in, unsigned short* __restrict__ out, int n) {
  int i = (blockIdx.x * blockDim.x + threadIdx.x) * 8;
  if (i >= n) return;
  float4 a = *(const float4*)(in + i);
  float4 b = *(const float4*)(in + i + 4);
  ushort4 o0, o1;
  o0.x = f2bf(a.x); o0.y = f2bf(a.y); o0.z = f2bf(a.z); o0.w = f2bf(a.w);
  o1.x = f2bf(b.x); o1.y = f2bf(b.y); o1.z = f2bf(b.z); o1.w = f2bf(b.w);
  *(ushort4*)(out + i) = o0;
  *(ushort4*)(out + i + 4) = o1;
}

// ---------------- unified projection GEMM: C_z = X @ W_z^T + b_z, bf16 out ----------------
// z: 0=Vr, 1=Vi, 2=K, 3=Q
__global__ __launch_bounds__(256) void proj_all(
    const unsigned short* __restrict__ xb,
    const unsigned short* __restrict__ Wb,   // [4][1024][1024] bf16 concat
    const float* __restrict__ bvr, const float* __restrict__ bvi,
    const float* __restrict__ bk,  const float* __restrict__ bq,
    unsigned short* __restrict__ oVr, unsigned short* __restrict__ oVi,
    unsigned short* __restrict__ oK,  unsigned short* __restrict__ oQ) {
  const int m0 = blockIdx.x * 128;
  const int n0 = blockIdx.y * 128;
  const int z = blockIdx.z;
  const unsigned short* W = Wb + (size_t)z * DD * DD;
  const float* bias = (z == 0) ? bvr : (z == 1) ? bvi : (z == 2) ? bk : bq;
  unsigned short* out = (z == 0) ? oVr : (z == 1) ? oVi : (z == 2) ? oK : oQ;

  __shared__ __align__(16) unsigned short As[128 * 32];
  __shared__ __align__(16) unsigned short Bs[128 * 32];

  const int tid = threadIdx.x;
  const int w = tid >> 6, lane = tid & 63;
  const int wm = w >> 1, wn = w & 1;
  const int lq = lane >> 4, lr = lane & 15;
  const int srow = lane >> 2, scol = (lane & 3) * 8;

  f32x4 acc[4][4];
#pragma unroll
  for (int i = 0; i < 4; i++)
#pragma unroll
    for (int j = 0; j < 4; j++) acc[i][j] = (f32x4)(0.f);

  for (int k0 = 0; k0 < 1024; k0 += 32) {
#pragma unroll
    for (int s = 0; s < 2; s++) {
      int c = w * 2 + s;
      int row = c * 16 + srow;
      async16(xb + (size_t)(m0 + row) * 1024 + k0 + scol, (char*)As + c * 1024 + lane * 16);
      async16(W  + (size_t)(n0 + row) * 1024 + k0 + scol, (char*)Bs + c * 1024 + lane * 16);
    }
    __syncthreads();
    bf16x8 af[4], bfr[4];
#pragma unroll
    for (int i = 0; i < 4; i++) af[i]  = *(const bf16x8*)(As + (wm * 64 + i * 16 + lr) * 32 + lq * 8);
#pragma unroll
    for (int j = 0; j < 4; j++) bfr[j] = *(const bf16x8*)(Bs + (wn * 64 + j * 16 + lr) * 32 + lq * 8);
#pragma unroll
    for (int i = 0; i < 4; i++)
#pragma unroll
      for (int j = 0; j < 4; j++)
        acc[i][j] = __builtin_amdgcn_mfma_f32_16x16x32_bf16(af[i], bfr[j], acc[i][j], 0, 0, 0);
    __syncthreads();
  }
#pragma unroll
  for (int j = 0; j < 4; j++) {
    int col = n0 + wn * 64 + j * 16 + lr;
    float bv = bias[col];
#pragma unroll
    for (int i = 0; i < 4; i++) {
      int rowb = m0 + wm * 64 + i * 16 + lq * 4;
#pragma unroll
      for (int r = 0; r < 4; r++)
        out[(size_t)(rowb + r) * 1024 + col] = f2bf(acc[i][j][r] + bv);
    }
  }
}

// ---------------- GLU: V = Vr * tanh(softplus(Vi)), in place on Vr ----------------
__global__ void glu(unsigned short* __restrict__ V, const unsigned short* __restrict__ Vi, int n) {
  int i = (blockIdx.x * blockDim.x + threadIdx.x) * 8;
  if (i >= n) return;
  ushort4 r0 = *(const ushort4*)(V + i);
  ushort4 r1 = *(const ushort4*)(V + i + 4);
  ushort4 i0 = *(const ushort4*)(Vi + i);
  ushort4 i1 = *(const ushort4*)(Vi + i + 4);
  unsigned short vr[8] = {r0.x, r0.y, r0.z, r0.w, r1.x, r1.y, r1.z, r1.w};
  unsigned short vi[8] = {i0.x, i0.y, i0.z, i0.w, i1.x, i1.y, i1.z, i1.w};
  unsigned short o[8];
#pragma unroll
  for (int k = 0; k < 8; k++) {
    float a = bf2f(vr[k]), b = bf2f(vi[k]);
    // tanh(softplus(b)) = u/(u+2), u = e^b*(e^b+2); clamp for large b
    float g;
    if (b > 10.f) g = 1.f;
    else { float t = __expf(b); float u = t * (t + 2.f); g = u / (u + 2.f); }
    o[k] = f2bf(a * g);
  }
  *(ushort4*)(V + i)     = make_ushort4(o[0], o[1], o[2], o[3]);
  *(ushort4*)(V + i + 4) = make_ushort4(o[4], o[5], o[6], o[7]);
}

// ---------------- tiled transpose [b][n][d] -> [b][d][n] ----------------
__global__ void transpose_kq(const unsigned short* __restrict__ Kbuf,
                             const unsigned short* __restrict__ Qbuf,
                             unsigned short* __restrict__ Kt,
                             unsigned short* __restrict__ Qt) {
  __shared__ unsigned short tile[64][65];
  int n0 = blockIdx.x * 64, d0 = blockIdx.y * 64;
  int b = blockIdx.z & 7, which = blockIdx.z >> 3;
  const unsigned short* src = (which ? Qbuf : Kbuf) + (size_t)b * NSEQ * DD;
  unsigned short* dst = (which ? Qt : Kt) + (size_t)b * DD * NSEQ;
  int tx = threadIdx.x, ty = threadIdx.y;
#pragma unroll
  for (int i = 0; i < 64; i += 4)
    tile[ty + i][tx] = src[(size_t)(n0 + ty + i) * DD + d0 + tx];
  __syncthreads();
#pragma unroll
  for (int i = 0; i < 64; i += 4)
    dst[(size_t)(d0 + ty + i) * NSEQ + n0 + tx] = tile[tx][ty + i];
}

// ---------------- per-channel reciprocal norms ----------------
__global__ __launch_bounds__(256) void colnorm(const unsigned short* __restrict__ Kt,
                                               const unsigned short* __restrict__ Qt,
                                               float* __restrict__ rn) {
  int row = blockIdx.x;          // b*1024 + chan
  int which = blockIdx.y;        // 0 = K, 1 = Q
  const unsigned short* src = (which ? Qt : Kt) + (size_t)row * NSEQ;
  float s = 0.f;
  for (int i = threadIdx.x; i < NSEQ; i += 256) { float v = bf2f(src[i]); s += v * v; }
  for (int off = 32; off; off >>= 1) s += __shfl_down(s, off, 64);
  __shared__ float wsum[4];
  int w = threadIdx.x >> 6, lane = threadIdx.x & 63;
  if (lane == 0) wsum[w] = s;
  __syncthreads();
  if (threadIdx.x == 0) {
    float t = wsum[0] + wsum[1] + wsum[2] + wsum[3];
    rn[which * (BB * DD) + row] = 1.f / (sqrtf(t) + 1e-5f);
  }
}

// ---------------- feature attention: fat[b][e][d] = smu(scale * q_e . k_d) ----------------
__global__ __launch_bounds__(256) void attn_gemm(
    const unsigned short* __restrict__ Qt, const unsigned short* __restrict__ Kt,
    const float* __restrict__ rn, unsigned short* __restrict__ fat) {
  const int b = blockIdx.z;
  const int e0 = blockIdx.y * 128;  // rows (query chan)
  const int d0 = blockIdx.x * 128;  // cols (key chan)
  const unsigned short* A  = Qt + (size_t)b * DD * NSEQ;
  const unsigned short* Bm = Kt + (size_t)b * DD * NSEQ;
  unsigned short* out = fat + (size_t)b * DD * DD;

  __shared__ __align__(16) unsigned short As[128 * 32];
  __shared__ __align__(16) unsigned short Bs[128 * 32];

  const int tid = threadIdx.x;
  const int w = tid >> 6, lane = tid & 63;
  const int wm = w >> 1, wn = w & 1;
  const int lq = lane >> 4, lr = lane & 15;
  const int srow = lane >> 2, scol = (lane & 3) * 8;

  f32x4 acc[4][4];
#pragma unroll
  for (int i = 0; i < 4; i++)
#pragma unroll
    for (int j = 0; j < 4; j++) acc[i][j] = (f32x4)(0.f);

  for (int k0 = 0; k0 < NSEQ; k0 += 32) {
#pragma unroll
    for (int s = 0; s < 2; s++) {
      int c = w * 2 + s;
      int row = c * 16 + srow;
      async16(A  + (size_t)(e0 + row) * NSEQ + k0 + scol, (char*)As + c * 1024 + lane * 16);
      async16(Bm + (size_t)(d0 + row) * NSEQ + k0 + scol, (char*)Bs + c * 1024 + lane * 16);
    }
    __syncthreads();
    bf16x8 af[4], bfr[4];
#pragma unroll
    for (int i = 0; i < 4; i++) af[i]  = *(const bf16x8*)(As + (wm * 64 + i * 16 + lr) * 32 + lq * 8);
#pragma unroll
    for (int j = 0; j < 4; j++) bfr[j] = *(const bf16x8*)(Bs + (wn * 64 + j * 16 + lr) * 32 + lq * 8);
#pragma unroll
    for (int i = 0; i < 4; i++)
#pragma unroll
      for (int j = 0; j < 4; j++)
        acc[i][j] = __builtin_amdgcn_mfma_f32_16x16x32_bf16(af[i], bfr[j], acc[i][j], 0, 0, 0);
    __syncthreads();
  }
#pragma unroll
  for (int j = 0; j < 4; j++) {
    int col = d0 + wn * 64 + j * 16 + lr;
    float rk = rn[b * DD + col];
#pragma unroll
    for (int i = 0; i < 4; i++) {
      int rowb = e0 + wm * 64 + i * 16 + lq * 4;
#pragma unroll
      for (int r = 0; r < 4; r++) {
        float rq = rn[BB * DD + b * DD + rowb + r];
        float c = acc[i][j][r] * rq * rk;
        c = (c > 0.f) ? c : 0.25f * c;   // smu with mu=1e6 == leaky relu (erf saturated)
        out[(size_t)(rowb + r) * DD + col] = f2bf(c);
      }
    }
  }
}

// ---------------- output GEMM: out[m][e] = sum_d V[m][d] * fa[d][e] (fat holds fa^T) ----------------
__global__ __launch_bounds__(256) void out_gemm(
    const unsigned short* __restrict__ V, const unsigned short* __restrict__ fat,
    float* __restrict__ out) {
  const int m0 = blockIdx.x * 128;
  const int e0 = blockIdx.y * 128;
  const int b = m0 >> 12;  // /4096
  const unsigned short* Bm = fat + (size_t)b * DD * DD;

  __shared__ __align__(16) unsigned short As[128 * 32];
  __shared__ __align__(16) unsigned short Bs[128 * 32];

  const int tid = threadIdx.x;
  const int w = tid >> 6, lane = tid & 63;
  const int wm = w >> 1, wn = w & 1;
  const int lq = lane >> 4, lr = lane & 15;
  const int srow = lane >> 2, scol = (lane & 3) * 8;

  f32x4 acc[4][4];
#pragma unroll
  for (int i = 0; i < 4; i++)
#pragma unroll
    for (int j = 0; j < 4; j++) acc[i][j] = (f32x4)(0.f);

  for (int k0 = 0; k0 < DD; k0 += 32) {
#pragma unroll
    for (int s = 0; s < 2; s++) {
      int c = w * 2 + s;
      int row = c * 16 + srow;
      async16(V  + (size_t)(m0 + row) * DD + k0 + scol, (char*)As + c * 1024 + lane * 16);
      async16(Bm + (size_t)(e0 + row) * DD + k0 + scol, (char*)Bs + c * 1024 + lane * 16);
    }
    __syncthreads();
    bf16x8 af[4], bfr[4];
#pragma unroll
    for (int i = 0; i < 4; i++) af[i]  = *(const bf16x8*)(As + (wm * 64 + i * 16 + lr) * 32 + lq * 8);
#pragma unroll
    for (int j = 0; j < 4; j++) bfr[j] = *(const bf16x8*)(Bs + (wn * 64 + j * 16 + lr) * 32 + lq * 8);
#pragma unroll
    for (int i = 0; i < 4; i++)
#pragma unroll
      for (int j = 0; j < 4; j++)
        acc[i][j] = __builtin_amdgcn_mfma_f32_16x16x32_bf16(af[i], bfr[j], acc[i][j], 0, 0, 0);
    __syncthreads();
  }
#pragma unroll
  for (int j = 0; j < 4; j++) {
    int col = e0 + wn * 64 + j * 16 + lr;
#pragma unroll
    for (int i = 0; i < 4; i++) {
      int rowb = m0 + wm * 64 + i * 16 + lq * 4;
#pragma unroll
      for (int r = 0; r < 4; r++)
        out[(size_t)(rowb + r) * DD + col] = acc[i][j][r];
    }
  }
}

extern "C" void kernel_launch(void* const* d_in, const int* in_sizes, int n_in,
                              void* d_out, int out_size, void* d_ws, size_t ws_size,
                              hipStream_t stream) {
  const float* x   = (const float*)d_in[0];
  const float* Wvr = (const float*)d_in[1];
  const float* bvr = (const float*)d_in[2];
  const float* Wvi = (const float*)d_in[3];
  const float* bvi = (const float*)d_in[4];
  const float* Wk  = (const float*)d_in[5];
  const float* bk  = (const float*)d_in[6];
  const float* Wq  = (const float*)d_in[7];
  const float* bq  = (const float*)d_in[8];
  float* out = (float*)d_out;

  char* p = (char*)d_ws;
  unsigned short* xb = (unsigned short*)p; p += (size_t)MTOT * DD * 2;     // 64 MiB
  unsigned short* Wb = (unsigned short*)p; p += 4ull * DD * DD * 2;        // 8 MiB
  unsigned short* Kt = (unsigned short*)p; p += (size_t)BB * DD * NSEQ * 2; // 64 MiB
  unsigned short* Qt = (unsigned short*)p; p += (size_t)BB * DD * NSEQ * 2; // 64 MiB
  unsigned short* Vb = (unsigned short*)p; p += (size_t)MTOT * DD * 2;     // 64 MiB
  unsigned short* fat = (unsigned short*)p; p += (size_t)BB * DD * DD * 2; // 16 MiB
  float* rn = (float*)p; p += 2ull * BB * DD * sizeof(float);              // 64 KiB

  // K,Q (natural layout, bf16) staged inside d_out scratch: 2 * 64 MiB == out buffer
  unsigned short* Kbuf = (unsigned short*)d_out;
  unsigned short* Qbuf = Kbuf + (size_t)MTOT * DD;
  // Vi staged in the Kt region (dead until transpose_kq runs)
  unsigned short* ViBuf = Kt;

  int nx = MTOT * DD;        // 33,554,432
  int nw = DD * DD;          // 1,048,576
  cvt_bf16<<<nx / 8 / 256, 256, 0, stream>>>(x, xb, nx);
  cvt_bf16<<<nw / 8 / 256, 256, 0, stream>>>(Wvr, Wb + 0ull * nw, nw);
  cvt_bf16<<<nw / 8 / 256, 256, 0, stream>>>(Wvi, Wb + 1ull * nw, nw);
  cvt_bf16<<<nw / 8 / 256, 256, 0, stream>>>(Wk,  Wb + 2ull * nw, nw);
  cvt_bf16<<<nw / 8 / 256, 256, 0, stream>>>(Wq,  Wb + 3ull * nw, nw);

  // all 4 projections in one dispatch: z=0 Vr->Vb, z=1 Vi->ViBuf(Kt), z=2 K->Kbuf, z=3 Q->Qbuf
  proj_all<<<dim3(MTOT / 128, DD / 128, 4), 256, 0, stream>>>(
      xb, Wb, bvr, bvi, bk, bq, Vb, ViBuf, Kbuf, Qbuf);

  glu<<<nx / 8 / 256, 256, 0, stream>>>(Vb, ViBuf, nx);

  transpose_kq<<<dim3(NSEQ / 64, DD / 64, 16), dim3(64, 4), 0, stream>>>(Kbuf, Qbuf, Kt, Qt);
  colnorm<<<dim3(BB * DD, 2), 256, 0, stream>>>(Kt, Qt, rn);

  attn_gemm<<<dim3(DD / 128, DD / 128, BB), 256, 0, stream>>>(Qt, Kt, rn, fat);
  out_gemm<<<dim3(MTOT / 128, DD / 128), 256, 0, stream>>>(Vb, fat, out);
}

// Round 3
// 941.192 us; speedup vs baseline: 1.3818x; 1.0405x over previous
//
#include <hip/hip_runtime.h>
#include <math.h>

typedef __bf16 bf16x8 __attribute__((ext_vector_type(8)));
typedef float f32x4 __attribute__((ext_vector_type(4)));

#define MTOT 32768   // B*N
#define DD   1024
#define NSEQ 4096
#define BB   8
#define SP   136     // padded LDS stride (shorts) for the 128x128 transpose tile

__device__ __forceinline__ void async16(const void* gp, void* lp) {
  __builtin_amdgcn_global_load_lds(
      (__attribute__((address_space(1))) void*)(const_cast<void*>(gp)),
      (__attribute__((address_space(3))) void*)(lp), 16, 0, 0);
}

__device__ __forceinline__ unsigned short f2bf(float f) {
  union { float f; unsigned int u; } v; v.f = f;
  unsigned int r = v.u + 0x7fffu + ((v.u >> 16) & 1u);
  return (unsigned short)(r >> 16);
}
__device__ __forceinline__ float bf2f(unsigned short u) {
  union { unsigned int u; float f; } v; v.u = ((unsigned int)u) << 16; return v.f;
}

// ---------------- fp32 -> bf16 convert (x) ----------------
__global__ void cvt_bf16(const float* __restrict__ in, unsigned short* __restrict__ out, int n) {
  int i = (blockIdx.x * blockDim.x + threadIdx.x) * 8;
  if (i >= n) return;
  float4 a = *(const float4*)(in + i);
  float4 b = *(const float4*)(in + i + 4);
  ushort4 o0, o1;
  o0.x = f2bf(a.x); o0.y = f2bf(a.y); o0.z = f2bf(a.z); o0.w = f2bf(a.w);
  o1.x = f2bf(b.x); o1.y = f2bf(b.y); o1.z = f2bf(b.z); o1.w = f2bf(b.w);
  *(ushort4*)(out + i) = o0;
  *(ushort4*)(out + i + 4) = o1;
}

// ---------------- weights: 4 matrices in one dispatch ----------------
__global__ void cvt_w(const float* __restrict__ w0, const float* __restrict__ w1,
                      const float* __restrict__ w2, const float* __restrict__ w3,
                      unsigned short* __restrict__ out) {
  int z = blockIdx.y;
  const float* in = (z == 0) ? w0 : (z == 1) ? w1 : (z == 2) ? w2 : w3;
  int i = (blockIdx.x * blockDim.x + threadIdx.x) * 8;
  float4 a = *(const float4*)(in + i);
  float4 b = *(const float4*)(in + i + 4);
  ushort4 o0, o1;
  o0.x = f2bf(a.x); o0.y = f2bf(a.y); o0.z = f2bf(a.z); o0.w = f2bf(a.w);
  o1.x = f2bf(b.x); o1.y = f2bf(b.y); o1.z = f2bf(b.z); o1.w = f2bf(b.w);
  unsigned short* o = out + (size_t)z * DD * DD;
  *(ushort4*)(o + i) = o0;
  *(ushort4*)(o + i + 4) = o1;
}

// ---------------- unified projection GEMM ----------------
// z: 0=Vr (natural), 1=Vi (natural), 2=K (transposed out + sumsq), 3=Q (same)
__global__ __launch_bounds__(256) void proj_all(
    const unsigned short* __restrict__ xb,
    const unsigned short* __restrict__ Wb,
    const float* __restrict__ bvr, const float* __restrict__ bvi,
    const float* __restrict__ bk,  const float* __restrict__ bq,
    unsigned short* __restrict__ oVr, unsigned short* __restrict__ oVi,
    unsigned short* __restrict__ Kt,  unsigned short* __restrict__ Qt,
    float* __restrict__ rnacc) {
  const int m0 = blockIdx.x * 128;
  const int n0 = blockIdx.y * 128;
  const int z = blockIdx.z;
  const unsigned short* W = Wb + (size_t)z * DD * DD;
  const float* bias = (z == 0) ? bvr : (z == 1) ? bvi : (z == 2) ? bk : bq;

  __shared__ __align__(16) unsigned short smem[128 * SP];  // 34 KB; staging lives in front
  unsigned short* As = smem;             // 128x32 shorts (8 KB)
  unsigned short* Bs = smem + 128 * 32;  // 128x32 shorts (8 KB)

  const int tid = threadIdx.x;
  const int w = tid >> 6, lane = tid & 63;
  const int wm = w >> 1, wn = w & 1;
  const int lq = lane >> 4, lr = lane & 15;
  const int srow = lane >> 2, scol = (lane & 3) * 8;

  f32x4 acc[4][4];
#pragma unroll
  for (int i = 0; i < 4; i++)
#pragma unroll
    for (int j = 0; j < 4; j++) acc[i][j] = (f32x4)(0.f);

  for (int k0 = 0; k0 < 1024; k0 += 32) {
#pragma unroll
    for (int s = 0; s < 2; s++) {
      int c = w * 2 + s;
      int row = c * 16 + srow;
      async16(xb + (size_t)(m0 + row) * 1024 + k0 + scol, (char*)As + c * 1024 + lane * 16);
      async16(W  + (size_t)(n0 + row) * 1024 + k0 + scol, (char*)Bs + c * 1024 + lane * 16);
    }
    __syncthreads();
    bf16x8 af[4], bfr[4];
#pragma unroll
    for (int i = 0; i < 4; i++) af[i]  = *(const bf16x8*)(As + (wm * 64 + i * 16 + lr) * 32 + lq * 8);
#pragma unroll
    for (int j = 0; j < 4; j++) bfr[j] = *(const bf16x8*)(Bs + (wn * 64 + j * 16 + lr) * 32 + lq * 8);
#pragma unroll
    for (int i = 0; i < 4; i++)
#pragma unroll
      for (int j = 0; j < 4; j++)
        acc[i][j] = __builtin_amdgcn_mfma_f32_16x16x32_bf16(af[i], bfr[j], acc[i][j], 0, 0, 0);
    __syncthreads();
  }

  if (z < 2) {
    unsigned short* out = (z == 0) ? oVr : oVi;
#pragma unroll
    for (int j = 0; j < 4; j++) {
      int col = n0 + wn * 64 + j * 16 + lr;
      float bv = bias[col];
#pragma unroll
      for (int i = 0; i < 4; i++) {
        int rowb = m0 + wm * 64 + i * 16 + lq * 4;
#pragma unroll
        for (int r = 0; r < 4; r++)
          out[(size_t)(rowb + r) * 1024 + col] = f2bf(acc[i][j][r] + bv);
      }
    }
  } else {
    // transposed epilogue: LDS tile T[col][row], then coalesced store to [b][d][n]
    unsigned short* out = (z == 2) ? Kt : Qt;
    const int which = z - 2;
    const int b = m0 >> 12;
    const int nbase = m0 & 4095;
#pragma unroll
    for (int j = 0; j < 4; j++) {
      int cl = wn * 64 + j * 16 + lr;
      float bv = bias[n0 + cl];
#pragma unroll
      for (int i = 0; i < 4; i++) {
        int rowb = wm * 64 + i * 16 + lq * 4;
        ushort4 pk;
        pk.x = f2bf(acc[i][j][0] + bv); pk.y = f2bf(acc[i][j][1] + bv);
        pk.z = f2bf(acc[i][j][2] + bv); pk.w = f2bf(acc[i][j][3] + bv);
        *(ushort4*)(smem + cl * SP + rowb) = pk;   // 8B-aligned (SP%4==0, rowb%4==0)
      }
    }
    __syncthreads();
    // copy out: 16 lanes cover one d-row (128 n = 256B contiguous), 8 passes
#pragma unroll
    for (int p = 0; p < 8; p++) {
      int dl = p * 16 + (tid >> 4);
      int nc = (tid & 15) * 8;
      ushort4 v0 = *(const ushort4*)(smem + dl * SP + nc);
      ushort4 v1 = *(const ushort4*)(smem + dl * SP + nc + 4);
      *(ushort4*)(out + (size_t)(b * DD + n0 + dl) * NSEQ + nbase + nc)     = v0;
      *(ushort4*)(out + (size_t)(b * DD + n0 + dl) * NSEQ + nbase + nc + 4) = v1;
      float s = bf2f(v0.x)*bf2f(v0.x) + bf2f(v0.y)*bf2f(v0.y) + bf2f(v0.z)*bf2f(v0.z) + bf2f(v0.w)*bf2f(v0.w)
              + bf2f(v1.x)*bf2f(v1.x) + bf2f(v1.y)*bf2f(v1.y) + bf2f(v1.z)*bf2f(v1.z) + bf2f(v1.w)*bf2f(v1.w);
#pragma unroll
      for (int off = 1; off < 16; off <<= 1) s += __shfl_xor(s, off, 64);
      if ((tid & 15) == 0)
        atomicAdd(&rnacc[which * (BB * DD) + b * DD + n0 + dl], s);
    }
  }
}

// ---------------- finalize reciprocal norms ----------------
__global__ void finalize_rn(float* __restrict__ rn) {
  int i = blockIdx.x * blockDim.x + threadIdx.x;
  rn[i] = 1.f / (sqrtf(rn[i]) + 1e-5f);
}

// ---------------- GLU: V = Vr * tanh(softplus(Vi)), in place on Vr ----------------
__global__ void glu(unsigned short* __restrict__ V, const unsigned short* __restrict__ Vi, int n) {
  int i = (blockIdx.x * blockDim.x + threadIdx.x) * 8;
  if (i >= n) return;
  ushort4 r0 = *(const ushort4*)(V + i);
  ushort4 r1 = *(const ushort4*)(V + i + 4);
  ushort4 i0 = *(const ushort4*)(Vi + i);
  ushort4 i1 = *(const ushort4*)(Vi + i + 4);
  unsigned short vr[8] = {r0.x, r0.y, r0.z, r0.w, r1.x, r1.y, r1.z, r1.w};
  unsigned short vi[8] = {i0.x, i0.y, i0.z, i0.w, i1.x, i1.y, i1.z, i1.w};
  unsigned short o[8];
#pragma unroll
  for (int k = 0; k < 8; k++) {
    float a = bf2f(vr[k]), b = bf2f(vi[k]);
    float g;
    if (b > 10.f) g = 1.f;
    else { float t = __expf(b); float u = t * (t + 2.f); g = u / (u + 2.f); }
    o[k] = f2bf(a * g);
  }
  *(ushort4*)(V + i)     = make_ushort4(o[0], o[1], o[2], o[3]);
  *(ushort4*)(V + i + 4) = make_ushort4(o[4], o[5], o[6], o[7]);
}

// ---------------- feature attention: fat[b][e][d] = smu(q_e . k_d scaled) ----------------
__global__ __launch_bounds__(256) void attn_gemm(
    const unsigned short* __restrict__ Qt, const unsigned short* __restrict__ Kt,
    const float* __restrict__ rn, unsigned short* __restrict__ fat) {
  const int b = blockIdx.z;
  const int e0 = blockIdx.y * 128;
  const int d0 = blockIdx.x * 128;
  const unsigned short* A  = Qt + (size_t)b * DD * NSEQ;
  const unsigned short* Bm = Kt + (size_t)b * DD * NSEQ;
  unsigned short* out = fat + (size_t)b * DD * DD;

  __shared__ __align__(16) unsigned short As[128 * 32];
  __shared__ __align__(16) unsigned short Bs[128 * 32];

  const int tid = threadIdx.x;
  const int w = tid >> 6, lane = tid & 63;
  const int wm = w >> 1, wn = w & 1;
  const int lq = lane >> 4, lr = lane & 15;
  const int srow = lane >> 2, scol = (lane & 3) * 8;

  f32x4 acc[4][4];
#pragma unroll
  for (int i = 0; i < 4; i++)
#pragma unroll
    for (int j = 0; j < 4; j++) acc[i][j] = (f32x4)(0.f);

  for (int k0 = 0; k0 < NSEQ; k0 += 32) {
#pragma unroll
    for (int s = 0; s < 2; s++) {
      int c = w * 2 + s;
      int row = c * 16 + srow;
      async16(A  + (size_t)(e0 + row) * NSEQ + k0 + scol, (char*)As + c * 1024 + lane * 16);
      async16(Bm + (size_t)(d0 + row) * NSEQ + k0 + scol, (char*)Bs + c * 1024 + lane * 16);
    }
    __syncthreads();
    bf16x8 af[4], bfr[4];
#pragma unroll
    for (int i = 0; i < 4; i++) af[i]  = *(const bf16x8*)(As + (wm * 64 + i * 16 + lr) * 32 + lq * 8);
#pragma unroll
    for (int j = 0; j < 4; j++) bfr[j] = *(const bf16x8*)(Bs + (wn * 64 + j * 16 + lr) * 32 + lq * 8);
#pragma unroll
    for (int i = 0; i < 4; i++)
#pragma unroll
      for (int j = 0; j < 4; j++)
        acc[i][j] = __builtin_amdgcn_mfma_f32_16x16x32_bf16(af[i], bfr[j], acc[i][j], 0, 0, 0);
    __syncthreads();
  }
#pragma unroll
  for (int j = 0; j < 4; j++) {
    int col = d0 + wn * 64 + j * 16 + lr;
    float rk = rn[b * DD + col];
#pragma unroll
    for (int i = 0; i < 4; i++) {
      int rowb = e0 + wm * 64 + i * 16 + lq * 4;
#pragma unroll
      for (int r = 0; r < 4; r++) {
        float rq = rn[BB * DD + b * DD + rowb + r];
        float c = acc[i][j][r] * rq * rk;
        c = (c > 0.f) ? c : 0.25f * c;   // smu(mu=1e6) == leaky relu
        out[(size_t)(rowb + r) * DD + col] = f2bf(c);
      }
    }
  }
}

// ---------------- output GEMM: out[m][e] = sum_d V[m][d] * fat[e][d] ----------------
__global__ __launch_bounds__(256) void out_gemm(
    const unsigned short* __restrict__ V, const unsigned short* __restrict__ fat,
    float* __restrict__ out) {
  const int m0 = blockIdx.x * 128;
  const int e0 = blockIdx.y * 128;
  const int b = m0 >> 12;
  const unsigned short* Bm = fat + (size_t)b * DD * DD;

  __shared__ __align__(16) unsigned short As[128 * 32];
  __shared__ __align__(16) unsigned short Bs[128 * 32];

  const int tid = threadIdx.x;
  const int w = tid >> 6, lane = tid & 63;
  const int wm = w >> 1, wn = w & 1;
  const int lq = lane >> 4, lr = lane & 15;
  const int srow = lane >> 2, scol = (lane & 3) * 8;

  f32x4 acc[4][4];
#pragma unroll
  for (int i = 0; i < 4; i++)
#pragma unroll
    for (int j = 0; j < 4; j++) acc[i][j] = (f32x4)(0.f);

  for (int k0 = 0; k0 < DD; k0 += 32) {
#pragma unroll
    for (int s = 0; s < 2; s++) {
      int c = w * 2 + s;
      int row = c * 16 + srow;
      async16(V  + (size_t)(m0 + row) * DD + k0 + scol, (char*)As + c * 1024 + lane * 16);
      async16(Bm + (size_t)(e0 + row) * DD + k0 + scol, (char*)Bs + c * 1024 + lane * 16);
    }
    __syncthreads();
    bf16x8 af[4], bfr[4];
#pragma unroll
    for (int i = 0; i < 4; i++) af[i]  = *(const bf16x8*)(As + (wm * 64 + i * 16 + lr) * 32 + lq * 8);
#pragma unroll
    for (int j = 0; j < 4; j++) bfr[j] = *(const bf16x8*)(Bs + (wn * 64 + j * 16 + lr) * 32 + lq * 8);
#pragma unroll
    for (int i = 0; i < 4; i++)
#pragma unroll
      for (int j = 0; j < 4; j++)
        acc[i][j] = __builtin_amdgcn_mfma_f32_16x16x32_bf16(af[i], bfr[j], acc[i][j], 0, 0, 0);
    __syncthreads();
  }
#pragma unroll
  for (int j = 0; j < 4; j++) {
    int col = e0 + wn * 64 + j * 16 + lr;
#pragma unroll
    for (int i = 0; i < 4; i++) {
      int rowb = m0 + wm * 64 + i * 16 + lq * 4;
#pragma unroll
      for (int r = 0; r < 4; r++)
        out[(size_t)(rowb + r) * DD + col] = acc[i][j][r];
    }
  }
}

extern "C" void kernel_launch(void* const* d_in, const int* in_sizes, int n_in,
                              void* d_out, int out_size, void* d_ws, size_t ws_size,
                              hipStream_t stream) {
  const float* x   = (const float*)d_in[0];
  const float* Wvr = (const float*)d_in[1];
  const float* bvr = (const float*)d_in[2];
  const float* Wvi = (const float*)d_in[3];
  const float* bvi = (const float*)d_in[4];
  const float* Wk  = (const float*)d_in[5];
  const float* bk  = (const float*)d_in[6];
  const float* Wq  = (const float*)d_in[7];
  const float* bq  = (const float*)d_in[8];
  float* out = (float*)d_out;

  char* p = (char*)d_ws;
  unsigned short* xb  = (unsigned short*)p; p += (size_t)MTOT * DD * 2;      // 64 MiB
  unsigned short* Wb  = (unsigned short*)p; p += 4ull * DD * DD * 2;         // 8 MiB
  unsigned short* Kt  = (unsigned short*)p; p += (size_t)BB * DD * NSEQ * 2; // 64 MiB
  unsigned short* Qt  = (unsigned short*)p; p += (size_t)BB * DD * NSEQ * 2; // 64 MiB
  unsigned short* Vb  = (unsigned short*)p; p += (size_t)MTOT * DD * 2;      // 64 MiB
  unsigned short* fat = (unsigned short*)p; p += (size_t)BB * DD * DD * 2;   // 16 MiB
  float* rn = (float*)p; p += 2ull * BB * DD * sizeof(float);                // 64 KiB

  // Vi staged in d_out (128 MiB fp32 out buffer; first 64 MiB as bf16 scratch)
  unsigned short* ViBuf = (unsigned short*)d_out;

  int nx = MTOT * DD;
  int nw = DD * DD;
  cvt_bf16<<<nx / 8 / 256, 256, 0, stream>>>(x, xb, nx);
  cvt_w<<<dim3(nw / 8 / 256, 4), 256, 0, stream>>>(Wvr, Wvi, Wk, Wq, Wb);
  hipMemsetAsync(rn, 0, 2ull * BB * DD * sizeof(float), stream);

  proj_all<<<dim3(MTOT / 128, DD / 128, 4), 256, 0, stream>>>(
      xb, Wb, bvr, bvi, bk, bq, Vb, ViBuf, Kt, Qt, rn);

  glu<<<nx / 8 / 256, 256, 0, stream>>>(Vb, ViBuf, nx);
  finalize_rn<<<2 * BB * DD / 256, 256, 0, stream>>>(rn);

  attn_gemm<<<dim3(DD / 128, DD / 128, BB), 256, 0, stream>>>(Qt, Kt, rn, fat);
  out_gemm<<<dim3(MTOT / 128, DD / 128), 256, 0, stream>>>(Vb, fat, out);
}